// Round 13
// baseline (206.231 us; speedup 1.0000x reference)
//
#include <hip/hip_runtime.h>
#include <hip/hip_fp16.h>

#define NPTS    2000000
#define PIL     100000
#define BN_EPS_F 1e-3f

// counting-sort params
#define SHIFT   5
#define PPB     32                  // pillars per bucket
#define NBKT    3125                // PIL / PPB
#define NBAC    512                 // blocks for hist/scatter passes
#define CHUNK   3907                // ceil(NPTS / NBAC)
#define TILE    256                 // records per kD pipeline chunk

// d_ws dword-index offsets (ws ~1 GB proven by harness poison fills)
#define WPH_OFF    512              // 160 u32 (half2-packed folded weights)
#define BP_OFF     768              // 32 f
#define PART_OFF   1024             // 65*NBAC f (end 34,304)
#define TOTS_OFF   34816            // NBKT u32 (end 37,941)
#define STARTS_OFF 38400            // NBKT+1 u32 (end 41,526)
#define HIST_OFF   49152            // NBAC*NBKT u32 = 1.6M (end 1,649,152)
#define PSA_OFF    1654784          // NPTS*4 u32 (uint4/record: 8 halfs) end 9,654,784
#define PSB_OFF    9654784          // NPTS*2 u32 (uint2/record: 2 halfs + meta) end 13,654,784

__device__ __forceinline__ constexpr int tri_idx(int j, int k) {
    return j * 10 - j * (j - 1) / 2 + (k - j);
}

__device__ __forceinline__ unsigned pk2(float x, float y) {
    __half2 h = __floats2half2_rn(x, y);
    return *reinterpret_cast<unsigned*>(&h);
}
__device__ __forceinline__ float2 uph2(unsigned u) {
    __half2 h = *reinterpret_cast<__half2*>(&u);
    return __half22float2(h);
}

// ---------------- kA: bucket histogram only (reads unq, 8 MB) ----------------
__global__ __launch_bounds__(512) void kA_hist(const int* __restrict__ unq,
                                               unsigned* __restrict__ hist)
{
    __shared__ unsigned h[NBKT];
    for (int i = threadIdx.x; i < NBKT; i += 512) h[i] = 0u;
    __syncthreads();
    const int lo = blockIdx.x * CHUNK;
    const int hi = min(lo + CHUNK, NPTS);
    for (int t = lo + threadIdx.x; t < hi; t += 512)
        atomicAdd(&h[unq[t] >> SHIFT], 1u);
    __syncthreads();
    for (int i = threadIdx.x; i < NBKT; i += 512)
        hist[(size_t)blockIdx.x * NBKT + i] = h[i];
}

// ---------------- kB1: per-bucket totals ----------------
__global__ __launch_bounds__(64) void kB1_colsum(const unsigned* __restrict__ hist,
                                                 unsigned* __restrict__ tots)
{
    const int c = blockIdx.x, lane = threadIdx.x;
    unsigned s = 0;
#pragma unroll
    for (int i = 0; i < NBAC / 64; ++i) s += hist[(size_t)(i * 64 + lane) * NBKT + c];
#pragma unroll
    for (int sh = 1; sh < 64; sh <<= 1) s += __shfl_xor(s, sh, 64);
    if (lane == 0) tots[c] = s;
}

// ---------------- kB2: scan totals (3125) -> bucket starts; 4 elems/thread ----------------
__global__ __launch_bounds__(1024) void kB2_scan(const unsigned* __restrict__ tots,
                                                 unsigned* __restrict__ starts)
{
    __shared__ unsigned ps[1024];
    const int t = threadIdx.x;
    unsigned v[4], sum = 0;
#pragma unroll
    for (int i = 0; i < 4; ++i) {
        int idx = t * 4 + i;
        v[i] = (idx < NBKT) ? tots[idx] : 0u;
        sum += v[i];
    }
    ps[t] = sum;
    __syncthreads();
    for (int d = 1; d < 1024; d <<= 1) {
        unsigned x = (t >= d) ? ps[t - d] : 0u;
        __syncthreads();
        ps[t] += x;
        __syncthreads();
    }
    unsigned excl = ps[t] - sum;
#pragma unroll
    for (int i = 0; i < 4; ++i) {
        int idx = t * 4 + i;
        if (idx < NBKT) starts[idx] = excl;
        excl += v[i];
    }
    if (t == 1023) starts[NBKT] = ps[1023];
}

// ---------------- kB3: expand per-(block,bucket) offsets IN PLACE over hist ----------------
__global__ __launch_bounds__(64) void kB3_expand(unsigned* __restrict__ hist,
                                                 const unsigned* __restrict__ starts)
{
    const int c = blockIdx.x, lane = threadIdx.x;
    unsigned hv[NBAC / 64];
    unsigned psum = 0;
#pragma unroll
    for (int i = 0; i < NBAC / 64; ++i) {
        hv[i] = hist[(size_t)(lane * (NBAC / 64) + i) * NBKT + c];
        psum += hv[i];
    }
    unsigned incl = psum;
#pragma unroll
    for (int s = 1; s < 64; s <<= 1) {
        unsigned v = __shfl_up(incl, s, 64);
        if (lane >= s) incl += v;
    }
    unsigned run = starts[c] + (incl - psum);
#pragma unroll
    for (int i = 0; i < NBAC / 64; ++i) {
        hist[(size_t)(lane * (NBAC / 64) + i) * NBKT + c] = run;
        run += hv[i];
    }
}

// ---------------- kC2: scatter 24B fp16 records into bucket order + 65 moments ----------------
__global__ __launch_bounds__(512) void kC2_scatter_mom(const float* __restrict__ in,
                                                       const int* __restrict__ unq,
                                                       const unsigned* __restrict__ off,
                                                       uint4* __restrict__ psA4,
                                                       uint2* __restrict__ psB2,
                                                       float* __restrict__ partial)
{
    __shared__ unsigned cur[NBKT];
    __shared__ float lds2[8][66];
    for (int i = threadIdx.x; i < NBKT; i += 512)
        cur[i] = off[(size_t)blockIdx.x * NBKT + i];
    __syncthreads();

    float acc[65];
#pragma unroll
    for (int i = 0; i < 65; ++i) acc[i] = 0.f;

    const int lo = blockIdx.x * CHUNK;
    const int hi = min(lo + CHUNK, NPTS);
    for (int t = lo + threadIdx.x; t < hi; t += 512) {
        int pil = unq[t];
        unsigned slot = atomicAdd(&cur[pil >> SHIFT], 1u);
        const float* px = in + (size_t)t * 10;
        float4 r0 = *reinterpret_cast<const float4*>(px);
        float4 r1 = *reinterpret_cast<const float4*>(px + 4);
        float2 r2 = *reinterpret_cast<const float2*>(px + 8);
        unsigned meta = ((unsigned)(pil & (PPB - 1)) << 21) | (unsigned)t;
        psA4[slot] = make_uint4(pk2(r0.x, r0.y), pk2(r0.z, r0.w),
                                pk2(r1.x, r1.y), pk2(r1.z, r1.w));
        psB2[slot] = make_uint2(pk2(r2.x, r2.y), meta);

        float xf[10] = { r0.x, r0.y, r0.z, r0.w, r1.x, r1.y, r1.z, r1.w, r2.x, r2.y };
#pragma unroll
        for (int j = 0; j < 10; ++j) acc[j] += xf[j];
        int o = 10;
#pragma unroll
        for (int j = 0; j < 10; ++j)
#pragma unroll
            for (int k = j; k < 10; ++k) acc[o++] += xf[j] * xf[k];
    }

#pragma unroll
    for (int i = 0; i < 65; ++i) {
        float v = acc[i];
#pragma unroll
        for (int s = 1; s < 64; s <<= 1) v += __shfl_xor(v, s, 64);
        acc[i] = v;
    }
    const int wid = threadIdx.x >> 6, lane = threadIdx.x & 63;
    if (lane == 0) {
#pragma unroll
        for (int i = 0; i < 65; ++i) lds2[wid][i] = acc[i];
    }
    __syncthreads();
    if (threadIdx.x < 65) {
        float s = 0.f;
#pragma unroll
        for (int wv = 0; wv < 8; ++wv) s += lds2[wv][threadIdx.x];
        partial[(size_t)threadIdx.x * NBAC + blockIdx.x] = s;
    }
}

// ---------------- k12: reduce partials + finalize BN (merged, one block) ----------------
__global__ __launch_bounds__(1024) void k12_final(const float* __restrict__ partial,
                                                  const float* __restrict__ W,
                                                  const float* __restrict__ b,
                                                  const float* __restrict__ gamma,
                                                  const float* __restrict__ beta,
                                                  unsigned* __restrict__ Wph,
                                                  float* __restrict__ bp)
{
    __shared__ float acc_s[65];
    const int t = threadIdx.x;
    if (t < 65 * 8) {                       // 8 lanes per accum entry
        const int e = t >> 3, j = t & 7;
        float s = 0.f;
        const float* p = partial + (size_t)e * NBAC + j * 64;
#pragma unroll
        for (int i = 0; i < 64; ++i) s += p[i];
#pragma unroll
        for (int sh = 1; sh < 8; sh <<= 1) s += __shfl_xor(s, sh, 64);
        if (j == 0) acc_s[e] = s;
    }
    __syncthreads();
    if (t < 32) {
        const int c = t;
        const float invN = 1.0f / (float)NPTS;
        float m[10], w[10];
#pragma unroll
        for (int k = 0; k < 10; ++k) m[k] = acc_s[k] * invN;
#pragma unroll
        for (int k = 0; k < 10; ++k) w[k] = W[c*10 + k];
        float mean = b[c];
#pragma unroll
        for (int k = 0; k < 10; ++k) mean += w[k] * m[k];
        float var = 0.f;
#pragma unroll
        for (int j = 0; j < 10; ++j) {
#pragma unroll
            for (int k = j; k < 10; ++k) {
                float Cjk = acc_s[10 + tri_idx(j, k)] * invN - m[j] * m[k];
                var += w[j] * w[k] * Cjk * ((j == k) ? 1.f : 2.f);
            }
        }
        float scale = gamma[c] * rsqrtf(var + BN_EPS_F);
#pragma unroll
        for (int j = 0; j < 5; ++j)
            Wph[c*5 + j] = pk2(w[2*j] * scale, w[2*j + 1] * scale);
        bp[c] = (b[c] - mean) * scale + beta[c];
    }
}

// ---------------- kD11: channel-per-lane, fp16 records, TILE=256 dbuf pipeline ----------------
#define STAGE_LOAD(ci_next, ra, rb)                                              \
    {                                                                            \
        size_t aB = (size_t)(s0 + (unsigned)(ci_next) * TILE) * 4;               \
        size_t bB = (size_t)(s0 + (unsigned)(ci_next) * TILE) * 2;               \
        if (aB + TILE * 4 <= gendA) {                                            \
            ra = *reinterpret_cast<const uint4*>(psA + aB + threadIdx.x * 4);    \
            rb = *reinterpret_cast<const uint2*>(psB + bB + threadIdx.x * 2);    \
        } else {                                                                 \
            size_t i0 = aB + threadIdx.x * 4;                                    \
            ra.x = psA[i0     < gendA ? i0     : gendA - 1];                     \
            ra.y = psA[i0 + 1 < gendA ? i0 + 1 : gendA - 1];                     \
            ra.z = psA[i0 + 2 < gendA ? i0 + 2 : gendA - 1];                     \
            ra.w = psA[i0 + 3 < gendA ? i0 + 3 : gendA - 1];                     \
            size_t i1 = bB + threadIdx.x * 2;                                    \
            rb.x = psB[i1     < gendB ? i1     : gendB - 1];                     \
            rb.y = psB[i1 + 1 < gendB ? i1 + 1 : gendB - 1];                     \
        }                                                                        \
    }
#define STAGE_WRITE(buf, ra, rb)                                                 \
    {                                                                            \
        *reinterpret_cast<uint4*>(&ldsA[buf][threadIdx.x * 4]) = ra;             \
        *reinterpret_cast<uint2*>(&ldsB[buf][threadIdx.x * 2]) = rb;             \
    }

__global__ __launch_bounds__(256) void kD11_reduce(const unsigned* __restrict__ psA,
                                                   const unsigned* __restrict__ psB,
                                                   const unsigned* __restrict__ starts,
                                                   const unsigned* __restrict__ Wph,
                                                   const float* __restrict__ bp,
                                                   float* __restrict__ out)
{
    __shared__ unsigned tab[PPB * 32];     // 4 KB; tab[pl*32+c] -> bank c
    __shared__ unsigned ldsA[2][TILE * 4]; // 2 x 4 KB
    __shared__ unsigned ldsB[2][TILE * 2]; // 2 x 2 KB
    for (int i = threadIdx.x; i < PPB * 32; i += 256) tab[i] = 0u;

    const int c   = threadIdx.x & 31;
    const int sub = threadIdx.x >> 5;      // 0..7
    float2 w[5];
#pragma unroll
    for (int j = 0; j < 5; ++j) w[j] = uph2(Wph[c * 5 + j]);
    const float bc = bp[c];

    const unsigned s0 = starts[blockIdx.x];
    const unsigned s1 = starts[blockIdx.x + 1];
    const unsigned nrec = s1 - s0;
    const int nch = (int)((nrec + TILE - 1) / TILE);
    const size_t gendA = (size_t)NPTS * 4;
    const size_t gendB = (size_t)NPTS * 2;

    uint4 ra; uint2 rb;
    // ---- phase 1: max into LDS table ----
    if (nch > 0) { STAGE_LOAD(0, ra, rb); STAGE_WRITE(0, ra, rb); }
    __syncthreads();
    for (int ci = 0; ci < nch; ++ci) {
        const bool more = (ci + 1 < nch);
        if (more) STAGE_LOAD(ci + 1, ra, rb);
        const unsigned* lA = ldsA[ci & 1];
        const unsigned* lB = ldsB[ci & 1];
        int rem = (int)nrec - ci * TILE;
        int rmax = rem < TILE ? rem : TILE;
        for (int r = sub; r < rmax; r += 8) {
            uint4 A = *reinterpret_cast<const uint4*>(lA + r * 4);
            uint2 B = *reinterpret_cast<const uint2*>(lB + r * 2);
            float2 x0 = uph2(A.x), x1 = uph2(A.y), x2 = uph2(A.z),
                   x3 = uph2(A.w), x4 = uph2(B.x);
            unsigned pl = (B.y >> 21) & (PPB - 1);
            float a = fmaf(x0.x, w[0].x, bc);
            a = fmaf(x0.y, w[0].y, a);
            a = fmaf(x1.x, w[1].x, a); a = fmaf(x1.y, w[1].y, a);
            a = fmaf(x2.x, w[2].x, a); a = fmaf(x2.y, w[2].y, a);
            a = fmaf(x3.x, w[3].x, a); a = fmaf(x3.y, w[3].y, a);
            a = fmaf(x4.x, w[4].x, a); a = fmaf(x4.y, w[4].y, a);
            a = fmaxf(a, 0.f);
            atomicMax(&tab[(pl << 5) + c], __float_as_uint(a));
        }
        __syncthreads();
        if (more) STAGE_WRITE((ci + 1) & 1, ra, rb);
        __syncthreads();
    }

    // ---- phase 2: recompute (bit-identical), combine, store original-order ----
    if (nch > 0) { STAGE_LOAD(0, ra, rb); STAGE_WRITE(0, ra, rb); }
    __syncthreads();
    for (int ci = 0; ci < nch; ++ci) {
        const bool more = (ci + 1 < nch);
        if (more) STAGE_LOAD(ci + 1, ra, rb);
        const unsigned* lA = ldsA[ci & 1];
        const unsigned* lB = ldsB[ci & 1];
        int rem = (int)nrec - ci * TILE;
        int rmax = rem < TILE ? rem : TILE;
        for (int r = sub; r < rmax; r += 8) {
            uint4 A = *reinterpret_cast<const uint4*>(lA + r * 4);
            uint2 B = *reinterpret_cast<const uint2*>(lB + r * 2);
            float2 x0 = uph2(A.x), x1 = uph2(A.y), x2 = uph2(A.z),
                   x3 = uph2(A.w), x4 = uph2(B.x);
            unsigned idx = B.y & 0x1FFFFFu;
            unsigned pl = (B.y >> 21) & (PPB - 1);
            float a = fmaf(x0.x, w[0].x, bc);
            a = fmaf(x0.y, w[0].y, a);
            a = fmaf(x1.x, w[1].x, a); a = fmaf(x1.y, w[1].y, a);
            a = fmaf(x2.x, w[2].x, a); a = fmaf(x2.y, w[2].y, a);
            a = fmaf(x3.x, w[3].x, a); a = fmaf(x3.y, w[3].y, a);
            a = fmaf(x4.x, w[4].x, a); a = fmaf(x4.y, w[4].y, a);
            a = fmaxf(a, 0.f);
            float mx = __uint_as_float(tab[(pl << 5) + c]);
            __builtin_nontemporal_store((a + mx) * 0.5f, &out[(size_t)idx * 32 + c]);
        }
        __syncthreads();
        if (more) STAGE_WRITE((ci + 1) & 1, ra, rb);
        __syncthreads();
    }
}

extern "C" void kernel_launch(void* const* d_in, const int* in_sizes, int n_in,
                              void* d_out, int out_size, void* d_ws, size_t ws_size,
                              hipStream_t stream)
{
    const float* in    = (const float*)d_in[0];
    const float* W     = (const float*)d_in[1];
    const float* b     = (const float*)d_in[2];
    const float* gamma = (const float*)d_in[3];
    const float* beta  = (const float*)d_in[4];
    const int*   unq   = (const int*)d_in[5];

    float* ws      = (float*)d_ws;
    unsigned* Wph  = (unsigned*)(ws + WPH_OFF);
    float* bp      = ws + BP_OFF;
    float* partial = ws + PART_OFF;
    unsigned* tots   = (unsigned*)(ws + TOTS_OFF);
    unsigned* starts = (unsigned*)(ws + STARTS_OFF);
    unsigned* hist   = (unsigned*)(ws + HIST_OFF);   // becomes offsets after kB3
    unsigned* psA    = (unsigned*)(ws + PSA_OFF);
    unsigned* psB    = (unsigned*)(ws + PSB_OFF);

    // bucket histogram (unq only) -> offsets
    kA_hist<<<NBAC, 512, 0, stream>>>(unq, hist);
    kB1_colsum<<<NBKT, 64, 0, stream>>>(hist, tots);
    kB2_scan<<<1, 1024, 0, stream>>>(tots, starts);
    kB3_expand<<<NBKT, 64, 0, stream>>>(hist, starts);
    // sort fp16 records + accumulate all 65 input moments in the same pass
    kC2_scatter_mom<<<NBAC, 512, 0, stream>>>(in, unq, hist,
                                              (uint4*)psA, (uint2*)psB, partial);
    // BN fold (merged reduce + finalize)
    k12_final<<<1, 1024, 0, stream>>>(partial, W, b, gamma, beta, Wph, bp);
    // per-bucket LDS segment-max + fused output (double-buffered fp16 pipeline)
    kD11_reduce<<<NBKT, 256, 0, stream>>>(psA, psB, starts, Wph, bp, (float*)d_out);
}

// Round 14
// 172.400 us; speedup vs baseline: 1.1962x; 1.1962x over previous
//
#include <hip/hip_runtime.h>
#include <hip/hip_fp16.h>

#define NPTS    2000000
#define PIL     100000
#define BN_EPS_F 1e-3f

// counting-sort params (R12-proven)
#define SHIFT   5
#define PPB     32                  // pillars per bucket
#define NBKT    3125                // PIL / PPB
#define NBAC    256                 // blocks for hist/scatter passes
#define CHUNK   7813                // ceil(NPTS / NBAC)
#define TILE    128                 // records per kD pipeline chunk

// d_ws dword-index offsets (ws ~1 GB proven by harness poison fills)
#define WPH_OFF    512              // 160 u32 (half2-packed folded weights)
#define BP_OFF     768              // 32 f
#define PART_OFF   1024             // 65*NBAC f (end 17,664)
#define TOTS_OFF   17920            // NBKT u32
#define STARTS_OFF 21248            // NBKT+1 u32
#define HIST_OFF   24576            // NBAC*NBKT u32 (end 824,576); kB3 rewrites in place
#define PSA_OFF    839680           // NPTS*4 u32 (uint4/record: 8 halfs)  end 8,839,680
#define PSB_OFF    8839680          // NPTS*2 u32 (uint2/record: 2 halfs + meta) end 12,839,680

#ifndef __has_builtin
#define __has_builtin(x) 0
#endif

__device__ __forceinline__ constexpr int tri_idx(int j, int k) {
    return j * 10 - j * (j - 1) / 2 + (k - j);
}

__device__ __forceinline__ unsigned pk2(float x, float y) {
    __half2 h = __floats2half2_rn(x, y);
    return *reinterpret_cast<unsigned*>(&h);
}
__device__ __forceinline__ float2 uph2(unsigned u) {
    __half2 h = *reinterpret_cast<__half2*>(&u);
    return __half22float2(h);
}

#if __has_builtin(__builtin_amdgcn_fdot2)
typedef _Float16 half2_t __attribute__((ext_vector_type(2)));
__device__ __forceinline__ half2_t h2(unsigned u) {
    return __builtin_bit_cast(half2_t, u);
}
#define KD_DOT(A, B, wh, bc, a)                                   \
    {                                                             \
        a = __builtin_amdgcn_fdot2(h2(A.x), wh[0], bc, false);    \
        a = __builtin_amdgcn_fdot2(h2(A.y), wh[1], a, false);     \
        a = __builtin_amdgcn_fdot2(h2(A.z), wh[2], a, false);     \
        a = __builtin_amdgcn_fdot2(h2(A.w), wh[3], a, false);     \
        a = __builtin_amdgcn_fdot2(h2(B.x), wh[4], a, false);     \
        a = fmaxf(a, 0.f);                                        \
    }
#define KD_WTYPE half2_t
#define KD_WLOAD(u) h2(u)
#else
#define KD_DOT(A, B, wh, bc, a)                                   \
    {                                                             \
        float2 x0 = uph2(A.x), x1 = uph2(A.y), x2 = uph2(A.z),    \
               x3 = uph2(A.w), x4 = uph2(B.x);                    \
        a = fmaf(x0.x, wh[0].x, bc);  a = fmaf(x0.y, wh[0].y, a); \
        a = fmaf(x1.x, wh[1].x, a);   a = fmaf(x1.y, wh[1].y, a); \
        a = fmaf(x2.x, wh[2].x, a);   a = fmaf(x2.y, wh[2].y, a); \
        a = fmaf(x3.x, wh[3].x, a);   a = fmaf(x3.y, wh[3].y, a); \
        a = fmaf(x4.x, wh[4].x, a);   a = fmaf(x4.y, wh[4].y, a); \
        a = fmaxf(a, 0.f);                                        \
    }
#define KD_WTYPE float2
#define KD_WLOAD(u) uph2(u)
#endif

// ---------------- kA: bucket histogram only (reads unq, 8 MB) ----------------
__global__ __launch_bounds__(512) void kA_hist(const int* __restrict__ unq,
                                               unsigned* __restrict__ hist)
{
    __shared__ unsigned h[NBKT];
    for (int i = threadIdx.x; i < NBKT; i += 512) h[i] = 0u;
    __syncthreads();
    const int lo = blockIdx.x * CHUNK;
    const int hi = min(lo + CHUNK, NPTS);
    for (int t = lo + threadIdx.x; t < hi; t += 512)
        atomicAdd(&h[unq[t] >> SHIFT], 1u);
    __syncthreads();
    for (int i = threadIdx.x; i < NBKT; i += 512)
        hist[(size_t)blockIdx.x * NBKT + i] = h[i];
}

// ---------------- kB1: per-bucket totals ----------------
__global__ __launch_bounds__(64) void kB1_colsum(const unsigned* __restrict__ hist,
                                                 unsigned* __restrict__ tots)
{
    const int c = blockIdx.x, lane = threadIdx.x;
    unsigned s = 0;
#pragma unroll
    for (int i = 0; i < NBAC / 64; ++i) s += hist[(size_t)(i * 64 + lane) * NBKT + c];
#pragma unroll
    for (int sh = 1; sh < 64; sh <<= 1) s += __shfl_xor(s, sh, 64);
    if (lane == 0) tots[c] = s;
}

// ---------------- kB2: scan totals (3125) -> bucket starts; 4 elems/thread ----------------
__global__ __launch_bounds__(1024) void kB2_scan(const unsigned* __restrict__ tots,
                                                 unsigned* __restrict__ starts)
{
    __shared__ unsigned ps[1024];
    const int t = threadIdx.x;
    unsigned v[4], sum = 0;
#pragma unroll
    for (int i = 0; i < 4; ++i) {
        int idx = t * 4 + i;
        v[i] = (idx < NBKT) ? tots[idx] : 0u;
        sum += v[i];
    }
    ps[t] = sum;
    __syncthreads();
    for (int d = 1; d < 1024; d <<= 1) {
        unsigned x = (t >= d) ? ps[t - d] : 0u;
        __syncthreads();
        ps[t] += x;
        __syncthreads();
    }
    unsigned excl = ps[t] - sum;
#pragma unroll
    for (int i = 0; i < 4; ++i) {
        int idx = t * 4 + i;
        if (idx < NBKT) starts[idx] = excl;
        excl += v[i];
    }
    if (t == 1023) starts[NBKT] = ps[1023];
}

// ---------------- kB3: expand per-(block,bucket) offsets IN PLACE over hist ----------------
__global__ __launch_bounds__(64) void kB3_expand(unsigned* __restrict__ hist,
                                                 const unsigned* __restrict__ starts)
{
    const int c = blockIdx.x, lane = threadIdx.x;
    unsigned hv[NBAC / 64];
    unsigned psum = 0;
#pragma unroll
    for (int i = 0; i < NBAC / 64; ++i) {
        hv[i] = hist[(size_t)(lane * (NBAC / 64) + i) * NBKT + c];
        psum += hv[i];
    }
    unsigned incl = psum;
#pragma unroll
    for (int s = 1; s < 64; s <<= 1) {
        unsigned v = __shfl_up(incl, s, 64);
        if (lane >= s) incl += v;
    }
    unsigned run = starts[c] + (incl - psum);
#pragma unroll
    for (int i = 0; i < NBAC / 64; ++i) {
        hist[(size_t)(lane * (NBAC / 64) + i) * NBKT + c] = run;
        run += hv[i];
    }
}

// ---------------- kC2: scatter 24B fp16 records into bucket order + 65 moments ----------------
__global__ __launch_bounds__(512) void kC2_scatter_mom(const float* __restrict__ in,
                                                       const int* __restrict__ unq,
                                                       const unsigned* __restrict__ off,
                                                       uint4* __restrict__ psA4,
                                                       uint2* __restrict__ psB2,
                                                       float* __restrict__ partial)
{
    __shared__ unsigned cur[NBKT];
    __shared__ float lds2[8][66];
    for (int i = threadIdx.x; i < NBKT; i += 512)
        cur[i] = off[(size_t)blockIdx.x * NBKT + i];
    __syncthreads();

    float acc[65];
#pragma unroll
    for (int i = 0; i < 65; ++i) acc[i] = 0.f;

    const int lo = blockIdx.x * CHUNK;
    const int hi = min(lo + CHUNK, NPTS);
    for (int t = lo + threadIdx.x; t < hi; t += 512) {
        int pil = unq[t];
        unsigned slot = atomicAdd(&cur[pil >> SHIFT], 1u);
        const float* px = in + (size_t)t * 10;
        float4 r0 = *reinterpret_cast<const float4*>(px);
        float4 r1 = *reinterpret_cast<const float4*>(px + 4);
        float2 r2 = *reinterpret_cast<const float2*>(px + 8);
        unsigned meta = ((unsigned)(pil & (PPB - 1)) << 21) | (unsigned)t;
        psA4[slot] = make_uint4(pk2(r0.x, r0.y), pk2(r0.z, r0.w),
                                pk2(r1.x, r1.y), pk2(r1.z, r1.w));
        psB2[slot] = make_uint2(pk2(r2.x, r2.y), meta);

        float xf[10] = { r0.x, r0.y, r0.z, r0.w, r1.x, r1.y, r1.z, r1.w, r2.x, r2.y };
#pragma unroll
        for (int j = 0; j < 10; ++j) acc[j] += xf[j];
        int o = 10;
#pragma unroll
        for (int j = 0; j < 10; ++j)
#pragma unroll
            for (int k = j; k < 10; ++k) acc[o++] += xf[j] * xf[k];
    }

#pragma unroll
    for (int i = 0; i < 65; ++i) {
        float v = acc[i];
#pragma unroll
        for (int s = 1; s < 64; s <<= 1) v += __shfl_xor(v, s, 64);
        acc[i] = v;
    }
    const int wid = threadIdx.x >> 6, lane = threadIdx.x & 63;
    if (lane == 0) {
#pragma unroll
        for (int i = 0; i < 65; ++i) lds2[wid][i] = acc[i];
    }
    __syncthreads();
    if (threadIdx.x < 65) {
        float s = 0.f;
#pragma unroll
        for (int wv = 0; wv < 8; ++wv) s += lds2[wv][threadIdx.x];
        partial[(size_t)threadIdx.x * NBAC + blockIdx.x] = s;
    }
}

// ---------------- k12: reduce partials + finalize BN (merged, one block) ----------------
__global__ __launch_bounds__(1024) void k12_final(const float* __restrict__ partial,
                                                  const float* __restrict__ W,
                                                  const float* __restrict__ b,
                                                  const float* __restrict__ gamma,
                                                  const float* __restrict__ beta,
                                                  unsigned* __restrict__ Wph,
                                                  float* __restrict__ bp)
{
    __shared__ float acc_s[65];
    const int t = threadIdx.x;
    if (t < 65 * 8) {                       // 8 lanes per accum entry; 32 values each
        const int e = t >> 3, j = t & 7;
        float s = 0.f;
        const float* p = partial + (size_t)e * NBAC + j * (NBAC / 8);
#pragma unroll
        for (int i = 0; i < NBAC / 8; ++i) s += p[i];
#pragma unroll
        for (int sh = 1; sh < 8; sh <<= 1) s += __shfl_xor(s, sh, 64);
        if (j == 0) acc_s[e] = s;
    }
    __syncthreads();
    if (t < 32) {
        const int c = t;
        const float invN = 1.0f / (float)NPTS;
        float m[10], w[10];
#pragma unroll
        for (int k = 0; k < 10; ++k) m[k] = acc_s[k] * invN;
#pragma unroll
        for (int k = 0; k < 10; ++k) w[k] = W[c*10 + k];
        float mean = b[c];
#pragma unroll
        for (int k = 0; k < 10; ++k) mean += w[k] * m[k];
        float var = 0.f;
#pragma unroll
        for (int j = 0; j < 10; ++j) {
#pragma unroll
            for (int k = j; k < 10; ++k) {
                float Cjk = acc_s[10 + tri_idx(j, k)] * invN - m[j] * m[k];
                var += w[j] * w[k] * Cjk * ((j == k) ? 1.f : 2.f);
            }
        }
        float scale = gamma[c] * rsqrtf(var + BN_EPS_F);
#pragma unroll
        for (int j = 0; j < 5; ++j)
            Wph[c*5 + j] = pk2(w[2*j] * scale, w[2*j + 1] * scale);
        bp[c] = (b[c] - mean) * scale + beta[c];
    }
}

// ---------------- kD12: channel-per-lane, fp16 records, fdot2, TILE=128 dbuf ----------------
#define STAGE_LOAD(ci_next, ra, rb)                                           \
    {                                                                         \
        size_t aB = (size_t)(s0 + (unsigned)(ci_next) * TILE) * 4;            \
        size_t bB = (size_t)(s0 + (unsigned)(ci_next) * TILE) * 2;            \
        if (aB + TILE * 4 <= gendA) {                                         \
            ra = *reinterpret_cast<const uint2*>(psA + aB + threadIdx.x * 2); \
            rb = psB[bB + threadIdx.x];                                       \
        } else {                                                              \
            size_t i0 = aB + threadIdx.x * 2;                                 \
            ra.x = psA[i0 < gendA ? i0 : gendA - 1];                          \
            ra.y = psA[i0 + 1 < gendA ? i0 + 1 : gendA - 1];                  \
            size_t i1 = bB + threadIdx.x;                                     \
            rb = psB[i1 < gendB ? i1 : gendB - 1];                            \
        }                                                                     \
    }
#define STAGE_WRITE(buf, ra, rb)                                              \
    {                                                                         \
        ldsA[buf][threadIdx.x * 2]     = ra.x;                                \
        ldsA[buf][threadIdx.x * 2 + 1] = ra.y;                                \
        ldsB[buf][threadIdx.x]         = rb;                                  \
    }

__global__ __launch_bounds__(256) void kD12_reduce(const unsigned* __restrict__ psA,
                                                   const unsigned* __restrict__ psB,
                                                   const unsigned* __restrict__ starts,
                                                   const unsigned* __restrict__ Wph,
                                                   const float* __restrict__ bp,
                                                   float* __restrict__ out)
{
    __shared__ unsigned tab[PPB * 32];     // 4 KB; tab[pl*32+c] -> bank c
    __shared__ unsigned ldsA[2][TILE * 4]; // 2 x 2 KB
    __shared__ unsigned ldsB[2][TILE * 2]; // 2 x 1 KB
    for (int i = threadIdx.x; i < PPB * 32; i += 256) tab[i] = 0u;

    const int c   = threadIdx.x & 31;
    const int sub = threadIdx.x >> 5;      // 0..7
    KD_WTYPE w[5];
#pragma unroll
    for (int j = 0; j < 5; ++j) w[j] = KD_WLOAD(Wph[c * 5 + j]);
    const float bc = bp[c];

    const unsigned s0 = starts[blockIdx.x];
    const unsigned s1 = starts[blockIdx.x + 1];
    const unsigned nrec = s1 - s0;
    const int nch = (int)((nrec + TILE - 1) / TILE);
    const size_t gendA = (size_t)NPTS * 4;
    const size_t gendB = (size_t)NPTS * 2;

    uint2 ra; unsigned rb;
    // ---- phase 1: max into LDS table ----
    if (nch > 0) { STAGE_LOAD(0, ra, rb); STAGE_WRITE(0, ra, rb); }
    __syncthreads();
    for (int ci = 0; ci < nch; ++ci) {
        const bool more = (ci + 1 < nch);
        if (more) STAGE_LOAD(ci + 1, ra, rb);
        const unsigned* lA = ldsA[ci & 1];
        const unsigned* lB = ldsB[ci & 1];
        int rem = (int)nrec - ci * TILE;
        int rmax = rem < TILE ? rem : TILE;
        for (int r = sub; r < rmax; r += 8) {
            uint4 A = *reinterpret_cast<const uint4*>(lA + r * 4);
            uint2 B = *reinterpret_cast<const uint2*>(lB + r * 2);
            unsigned pl = (B.y >> 21) & (PPB - 1);
            float a;
            KD_DOT(A, B, w, bc, a);
            atomicMax(&tab[(pl << 5) + c], __float_as_uint(a));
        }
        __syncthreads();
        if (more) STAGE_WRITE((ci + 1) & 1, ra, rb);
        __syncthreads();
    }

    // ---- phase 2: recompute (bit-identical), combine, store original-order ----
    if (nch > 0) { STAGE_LOAD(0, ra, rb); STAGE_WRITE(0, ra, rb); }
    __syncthreads();
    for (int ci = 0; ci < nch; ++ci) {
        const bool more = (ci + 1 < nch);
        if (more) STAGE_LOAD(ci + 1, ra, rb);
        const unsigned* lA = ldsA[ci & 1];
        const unsigned* lB = ldsB[ci & 1];
        int rem = (int)nrec - ci * TILE;
        int rmax = rem < TILE ? rem : TILE;
        for (int r = sub; r < rmax; r += 8) {
            uint4 A = *reinterpret_cast<const uint4*>(lA + r * 4);
            uint2 B = *reinterpret_cast<const uint2*>(lB + r * 2);
            unsigned idx = B.y & 0x1FFFFFu;
            unsigned pl = (B.y >> 21) & (PPB - 1);
            float a;
            KD_DOT(A, B, w, bc, a);
            float mx = __uint_as_float(tab[(pl << 5) + c]);
            __builtin_nontemporal_store((a + mx) * 0.5f, &out[(size_t)idx * 32 + c]);
        }
        __syncthreads();
        if (more) STAGE_WRITE((ci + 1) & 1, ra, rb);
        __syncthreads();
    }
}

extern "C" void kernel_launch(void* const* d_in, const int* in_sizes, int n_in,
                              void* d_out, int out_size, void* d_ws, size_t ws_size,
                              hipStream_t stream)
{
    const float* in    = (const float*)d_in[0];
    const float* W     = (const float*)d_in[1];
    const float* b     = (const float*)d_in[2];
    const float* gamma = (const float*)d_in[3];
    const float* beta  = (const float*)d_in[4];
    const int*   unq   = (const int*)d_in[5];

    float* ws      = (float*)d_ws;
    unsigned* Wph  = (unsigned*)(ws + WPH_OFF);
    float* bp      = ws + BP_OFF;
    float* partial = ws + PART_OFF;
    unsigned* tots   = (unsigned*)(ws + TOTS_OFF);
    unsigned* starts = (unsigned*)(ws + STARTS_OFF);
    unsigned* hist   = (unsigned*)(ws + HIST_OFF);   // becomes offsets after kB3
    unsigned* psA    = (unsigned*)(ws + PSA_OFF);
    unsigned* psB    = (unsigned*)(ws + PSB_OFF);

    // bucket histogram (unq only) -> offsets
    kA_hist<<<NBAC, 512, 0, stream>>>(unq, hist);
    kB1_colsum<<<NBKT, 64, 0, stream>>>(hist, tots);
    kB2_scan<<<1, 1024, 0, stream>>>(tots, starts);
    kB3_expand<<<NBKT, 64, 0, stream>>>(hist, starts);
    // sort fp16 records + accumulate all 65 input moments in the same pass
    kC2_scatter_mom<<<NBAC, 512, 0, stream>>>(in, unq, hist,
                                              (uint4*)psA, (uint2*)psB, partial);
    // BN fold (merged reduce + finalize)
    k12_final<<<1, 1024, 0, stream>>>(partial, W, b, gamma, beta, Wph, bp);
    // per-bucket LDS segment-max + fused output (double-buffered fp16 + fdot2)
    kD12_reduce<<<NBKT, 256, 0, stream>>>(psA, psB, starts, Wph, bp, (float*)d_out);
}